// Round 8
// baseline (728.555 us; speedup 1.0000x reference)
//
#include <hip/hip_runtime.h>
#include <hip/hip_bf16.h>
#include <math.h>

#define NN 2048
#define NEG 0.2f
#define LOG2E 1.44269504f

typedef short bf16x8 __attribute__((ext_vector_type(8)));
typedef float f32x16 __attribute__((ext_vector_type(16)));

__device__ __forceinline__ float dot4(float4 a, float4 b) {
  return a.x * b.x + a.y * b.y + a.z * b.z + a.w * b.w;
}

__device__ __forceinline__ unsigned short bfbits(float f) {
  union { __hip_bfloat16 b; unsigned short u; } c;
  c.b = __float2bfloat16(f);
  return c.u;
}

template <int VM>
__device__ __forceinline__ void waitv() {
  if constexpr (VM == 0) asm volatile("s_waitcnt vmcnt(0)" ::: "memory");
  else if constexpr (VM == 1) asm volatile("s_waitcnt vmcnt(1)" ::: "memory");
  else if constexpr (VM == 2) asm volatile("s_waitcnt vmcnt(2)" ::: "memory");
  else asm volatile("s_waitcnt vmcnt(3)" ::: "memory");
}

__device__ __forceinline__ void stage_frag(const unsigned short* g, char* l) {
  __builtin_amdgcn_global_load_lds(
      (const __attribute__((address_space(1))) unsigned int*)g,
      (__attribute__((address_space(3))) unsigned int*)l, 16, 0, 0);
}

// ---------------------------------------------------------------------------
// K1: x = bio @ initW^T + initb
// ---------------------------------------------------------------------------
__global__ __launch_bounds__(256) void k1_init(const float* __restrict__ bioA,
                                               const float* __restrict__ bioB,
                                               const float* __restrict__ W,
                                               const float* __restrict__ bias,
                                               float* __restrict__ xout) {
  __shared__ float As[32][36];
  __shared__ float Ws[32][132];
  const int t = threadIdx.x;
  const int m0 = blockIdx.x * 32;
  const float* A = (m0 < 8192) ? bioA : bioB;
  const int arow0 = (m0 < 8192) ? m0 : (m0 - 8192);
  const int og = t & 31, ig = t >> 5;
  float acc[4][4] = {};
  for (int kt = 0; kt < 256; kt += 32) {
    __syncthreads();
    {
      const int r = t >> 3, kq = t & 7;
      const float4 v = *(const float4*)&A[(arow0 + r) * 256 + kt + kq * 4];
      As[kq * 4 + 0][r] = v.x; As[kq * 4 + 1][r] = v.y;
      As[kq * 4 + 2][r] = v.z; As[kq * 4 + 3][r] = v.w;
    }
#pragma unroll
    for (int u = 0; u < 4; ++u) {
      const int f = u * 256 + t;
      const int o = f >> 3, kq = f & 7;
      const float4 v = *(const float4*)&W[o * 256 + kt + kq * 4];
      Ws[kq * 4 + 0][o] = v.x; Ws[kq * 4 + 1][o] = v.y;
      Ws[kq * 4 + 2][o] = v.z; Ws[kq * 4 + 3][o] = v.w;
    }
    __syncthreads();
#pragma unroll
    for (int kk = 0; kk < 32; ++kk) {
      const float4 a4 = *(const float4*)&As[kk][ig * 4];
      const float4 w4 = *(const float4*)&Ws[kk][og * 4];
      const float av[4] = {a4.x, a4.y, a4.z, a4.w};
      const float wv[4] = {w4.x, w4.y, w4.z, w4.w};
#pragma unroll
      for (int ii = 0; ii < 4; ++ii)
#pragma unroll
        for (int jj = 0; jj < 4; ++jj) acc[ii][jj] += av[ii] * wv[jj];
    }
  }
  const float4 b4 = *(const float4*)&bias[og * 4];
#pragma unroll
  for (int ii = 0; ii < 4; ++ii) {
    const int row = m0 + ig * 4 + ii;
    float4 o4;
    o4.x = acc[ii][0] + b4.x; o4.y = acc[ii][1] + b4.y;
    o4.z = acc[ii][2] + b4.z; o4.w = acc[ii][3] + b4.w;
    *(float4*)&xout[row * 128 + og * 4] = o4;
  }
}

// ---------------------------------------------------------------------------
// K2: y = x @ projW^T ; xhT2 bf16 tile-major [gb][h][m][jslot][k][j8]; s1,s2
// ---------------------------------------------------------------------------
__global__ __launch_bounds__(256) void k2_proj(const float* __restrict__ x,
                                               const float* __restrict__ W,
                                               const float* __restrict__ attw,
                                               unsigned short* __restrict__ xhT2,
                                               float* __restrict__ s1,
                                               float* __restrict__ s2) {
  __shared__ float As[32][36];
  __shared__ float Ws[32][132];
  const int t = threadIdx.x;
  const int m0 = blockIdx.x * 32;
  const int og = t & 31, ig = t >> 5;
  float acc[4][4] = {};
  for (int kt = 0; kt < 128; kt += 32) {
    __syncthreads();
    {
      const int r = t >> 3, kq = t & 7;
      const float4 v = *(const float4*)&x[(m0 + r) * 128 + kt + kq * 4];
      As[kq * 4 + 0][r] = v.x; As[kq * 4 + 1][r] = v.y;
      As[kq * 4 + 2][r] = v.z; As[kq * 4 + 3][r] = v.w;
    }
#pragma unroll
    for (int u = 0; u < 4; ++u) {
      const int f = u * 256 + t;
      const int o = f >> 3, kq = f & 7;
      const float4 v = *(const float4*)&W[o * 128 + kt + kq * 4];
      Ws[kq * 4 + 0][o] = v.x; Ws[kq * 4 + 1][o] = v.y;
      Ws[kq * 4 + 2][o] = v.z; Ws[kq * 4 + 3][o] = v.w;
    }
    __syncthreads();
#pragma unroll
    for (int kk = 0; kk < 32; ++kk) {
      const float4 a4 = *(const float4*)&As[kk][ig * 4];
      const float4 w4 = *(const float4*)&Ws[kk][og * 4];
      const float av[4] = {a4.x, a4.y, a4.z, a4.w};
      const float wv[4] = {w4.x, w4.y, w4.z, w4.w};
#pragma unroll
      for (int ii = 0; ii < 4; ++ii)
#pragma unroll
        for (int jj = 0; jj < 4; ++jj) acc[ii][jj] += av[ii] * wv[jj];
    }
  }
  const int h = og >> 3;
  const int k4i = (og & 7) * 4;
  const int g = m0 >> 13;
  const int bb = (m0 >> 11) & 3;
  const int gb = g * 4 + bb;
  const int n0 = (m0 & 2047) + ig * 4;
  const float4 w1 = *(const float4*)&attw[h * 64 + k4i];
  const float4 w2 = *(const float4*)&attw[h * 64 + 32 + k4i];
  float p1[4], p2[4];
#pragma unroll
  for (int ii = 0; ii < 4; ++ii) {
    float4 v;
    v.x = acc[ii][0]; v.y = acc[ii][1]; v.z = acc[ii][2]; v.w = acc[ii][3];
    p1[ii] = dot4(v, w1);
    p2[ii] = dot4(v, w2);
  }
  {
    const int mtile = n0 >> 4, jslot = (n0 >> 3) & 1, j8 = n0 & 7;
    const int base2 = ((((gb * 4 + h) * 128 + mtile) * 2 + jslot) * 32) * 8 + j8;
#pragma unroll
    for (int jj = 0; jj < 4; ++jj) {
      const int kin = k4i + jj;
      ushort4 u;
      u.x = bfbits(acc[0][jj]); u.y = bfbits(acc[1][jj]);
      u.z = bfbits(acc[2][jj]); u.w = bfbits(acc[3][jj]);
      *(ushort4*)&xhT2[base2 + kin * 8] = u;
    }
  }
#pragma unroll
  for (int s = 1; s < 8; s <<= 1) {
#pragma unroll
    for (int ii = 0; ii < 4; ++ii) {
      p1[ii] += __shfl_xor(p1[ii], s);
      p2[ii] += __shfl_xor(p2[ii], s);
    }
  }
  if ((og & 7) == 0) {
#pragma unroll
    for (int ii = 0; ii < 4; ++ii) {
      s1[(gb * 4 + h) * NN + n0 + ii] = p1[ii];
      s2[(gb * 4 + h) * NN + n0 + ii] = p2[ii];
    }
  }
}

// shared prologue body (s2 staging + deep-batched adjacency ballot-pack)
#define K3_PROLOGUE                                                           \
  {                                                                           \
    const float* s2g = s2w + gb * 4 * NN;                                     \
    _Pragma("unroll")                                                         \
    for (int u = 0; u < 4; ++u) {                                             \
      const int idx = u * 2048 + t * 4;                                       \
      float4 v = *(const float4*)&s2g[idx];                                   \
      v.x *= LOG2E; v.y *= LOG2E; v.z *= LOG2E; v.w *= LOG2E;                 \
      *(float4*)&s2L[idx] = v;                                                \
    }                                                                         \
  }                                                                           \
  _Pragma("unroll")                                                           \
  for (int r4 = 0; r4 < 4; ++r4) {                                            \
    const int r = wave * 4 + r4;                                              \
    const int* arow = adj + r * NN;                                           \
    int av[32];                                                               \
    _Pragma("unroll")                                                         \
    for (int w = 0; w < 32; ++w) av[w] = arow[w * 64 + lane];                 \
    _Pragma("unroll")                                                         \
    for (int w = 0; w < 32; ++w) {                                            \
      const unsigned long long mm = __ballot(av[w] > 0);                      \
      if (lane < 2) adjL[r * 66 + 2 * w + lane] = (unsigned int)(mm >> (32 * lane)); \
    }                                                                         \
  }

#define K3_SCORE_BODY(MM)                                                     \
    const int j0 = jlo + 16 * (MM) + jslot * 8;                               \
    const unsigned int wbits = adjL[i * 66 + ((jlo + 16 * (MM)) >> 5)];       \
    const unsigned int bits8 = wbits >> ((((MM) & 1) * 16) + jslot * 8);      \
    const float4 s2a = *(const float4*)&s2L[h * 2048 + j0];                   \
    const float4 s2b = *(const float4*)&s2L[h * 2048 + j0 + 4];               \
    const float sv[8] = {s2a.x, s2a.y, s2a.z, s2a.w,                          \
                         s2b.x, s2b.y, s2b.z, s2b.w};                         \
    union { bf16x8 v; unsigned short u[8]; } af;                              \
    float dsum = 0.f;                                                         \
    _Pragma("unroll")                                                         \
    for (int e = 0; e < 8; ++e) {                                             \
      float s = sc1v + sv[e];                                                 \
      s = fmaxf(s, NEG * s);                                                  \
      float pe = __builtin_amdgcn_exp2f(s);                                   \
      pe = ((bits8 >> e) & 1u) ? pe : 0.f;                                    \
      af.u[e] = bfbits(pe);                                                   \
      dsum += pe;                                                             \
    }                                                                         \
    den += dsum;

// ---------------------------------------------------------------------------
// K3: real kernel (same loop as r7; prologue load-batched)
// ---------------------------------------------------------------------------
__global__ __launch_bounds__(512) void k3_attn(const unsigned short* __restrict__ xhT2,
                                               const float* __restrict__ s1w,
                                               const float* __restrict__ s2w,
                                               const int* __restrict__ adjA,
                                               const int* __restrict__ adjB,
                                               const float* __restrict__ attb,
                                               const float* __restrict__ x,
                                               float* __restrict__ G) {
  __shared__ __align__(16) unsigned char smem3[75008];
  unsigned int* adjL = (unsigned int*)smem3;
  float* s2L = (float*)(smem3 + 8448);
  float* denR = (float*)(smem3 + 41216);
  char* bufs = (char*)(smem3 + 42240);
  float* accR = (float*)smem3;

  const int t = threadIdx.x;
  const int wave = t >> 6, lane = t & 63;
  const int blk = blockIdx.x;
  const int g = blk >> 8, b = (blk >> 6) & 3;
  const int i0 = (blk & 63) * 32;
  const int gb = g * 4 + b;
  const int* adj = (g ? adjB : adjA) + (b * NN + i0) * NN;
  K3_PROLOGUE
  __syncthreads();

  const int h = wave & 3;
  const int jhalf = wave >> 2;
  const int jlo = jhalf * 1024;
  const int i = lane & 31;
  const int jslot = lane >> 5;
  const float sc1v = (s1w[(gb * 4 + h) * NN + i0 + i] + attb[h]) * LOG2E;
  const unsigned short* bbase = xhT2 + (gb * 4 + h) * 65536 + jhalf * 32768 + lane * 8;
  char* wrb = bufs + wave * 4096;
  const char* rdb = wrb + lane * 16;
  f32x16 acc = {0.f, 0.f, 0.f, 0.f, 0.f, 0.f, 0.f, 0.f,
                0.f, 0.f, 0.f, 0.f, 0.f, 0.f, 0.f, 0.f};
  float den = 0.f;
  stage_frag(bbase + 0 * 512, wrb + 0 * 1024);
  stage_frag(bbase + 1 * 512, wrb + 1 * 1024);
  stage_frag(bbase + 2 * 512, wrb + 2 * 1024);

#define K3_STEP(MM, VM, DOSTAGE)                                              \
  {                                                                           \
    if (DOSTAGE)                                                              \
      stage_frag(bbase + ((MM) + 3) * 512, wrb + (((MM) + 3) & 3) * 1024);    \
    waitv<VM>();                                                              \
    const bf16x8 bcur = *(const bf16x8*)(rdb + ((MM) & 3) * 1024);            \
    K3_SCORE_BODY(MM)                                                         \
    acc = __builtin_amdgcn_mfma_f32_32x32x16_bf16(af.v, bcur, acc, 0, 0, 0);  \
  }

#pragma unroll 4
  for (int m = 0; m <= 60; ++m) K3_STEP(m, 3, true);
  K3_STEP(61, 2, false);
  K3_STEP(62, 1, false);
  K3_STEP(63, 0, false);
#undef K3_STEP

  den += __shfl_xor(den, 32);
  if (lane < 32) denR[(h * 2 + jhalf) * 32 + lane] = den;
  __syncthreads();
  if (jhalf == 1) {
#pragma unroll
    for (int r = 0; r < 16; ++r) accR[(h * 16 + r) * 65 + lane] = acc[r];
  }
  __syncthreads();
  if (jhalf == 0) {
#pragma unroll
    for (int r = 0; r < 16; ++r) {
      const int row = (r & 3) + 8 * (r >> 2) + 4 * jslot;
      const float dinv = 1.f / (denR[(h * 2 + 0) * 32 + row] + denR[(h * 2 + 1) * 32 + row]);
      const int off = (gb * NN + i0 + row) * 128 + h * 32 + i;
      const float av2 = acc[r] + accR[(h * 16 + r) * 65 + lane];
      G[off] = fmaxf(av2 * dinv, 0.f) + x[off];
    }
  }
}

// ---------------------------------------------------------------------------
// PROBE A: prologue only, x8
// ---------------------------------------------------------------------------
__global__ __launch_bounds__(512) void k3p_stage(const float* __restrict__ s2w,
                                                 const int* __restrict__ adjA,
                                                 const int* __restrict__ adjB,
                                                 float* __restrict__ po) {
  __shared__ __align__(16) unsigned char smem3[75008];
  unsigned int* adjL = (unsigned int*)smem3;
  float* s2L = (float*)(smem3 + 8448);
  const int t = threadIdx.x;
  const int wave = t >> 6, lane = t & 63;
  const int blk = blockIdx.x;
  const int g = blk >> 8, b = (blk >> 6) & 3;
  const int i0 = (blk & 63) * 32;
  const int gb = g * 4 + b;
  const int* adj = (g ? adjB : adjA) + (b * NN + i0) * NN;
  for (int rep = 0; rep < 8; ++rep) {
    K3_PROLOGUE
  }
  __syncthreads();
  po[blk * 512 + t] = s2L[(t * 5) & 8191] + (float)adjL[(t * 3) % 2112];
}

// ---------------------------------------------------------------------------
// PROBE B: prologue + score chain only (no stage/ds_read/MFMA), loop x4
// ---------------------------------------------------------------------------
__global__ __launch_bounds__(512) void k3p_score(const float* __restrict__ s1w,
                                                 const float* __restrict__ s2w,
                                                 const int* __restrict__ adjA,
                                                 const int* __restrict__ adjB,
                                                 const float* __restrict__ attb,
                                                 float* __restrict__ po) {
  __shared__ __align__(16) unsigned char smem3[75008];
  unsigned int* adjL = (unsigned int*)smem3;
  float* s2L = (float*)(smem3 + 8448);
  const int t = threadIdx.x;
  const int wave = t >> 6, lane = t & 63;
  const int blk = blockIdx.x;
  const int g = blk >> 8, b = (blk >> 6) & 3;
  const int i0 = (blk & 63) * 32;
  const int gb = g * 4 + b;
  const int* adj = (g ? adjB : adjA) + (b * NN + i0) * NN;
  K3_PROLOGUE
  __syncthreads();
  const int h = wave & 3;
  const int jhalf = wave >> 2;
  const int jlo = jhalf * 1024;
  const int i = lane & 31;
  const int jslot = lane >> 5;
  const float sc1v = (s1w[(gb * 4 + h) * NN + i0 + i] + attb[h]) * LOG2E;
  float den = 0.f;
  unsigned int keep = 0;
  for (int rep = 0; rep < 4; ++rep) {
#pragma unroll 4
    for (int m = 0; m < 64; ++m) {
      K3_SCORE_BODY(m)
      keep ^= af.u[0] ^ af.u[3] ^ af.u[7];
    }
  }
  po[blk * 512 + t] = den + (float)(keep & 0xff);
}

// ---------------------------------------------------------------------------
// PROBE D: prologue + full loop minus global staging, minus clobbers, x4
// ---------------------------------------------------------------------------
__global__ __launch_bounds__(512) void k3p_chain(const float* __restrict__ s1w,
                                                 const float* __restrict__ s2w,
                                                 const int* __restrict__ adjA,
                                                 const int* __restrict__ adjB,
                                                 const float* __restrict__ attb,
                                                 float* __restrict__ po) {
  __shared__ __align__(16) unsigned char smem3[75008];
  unsigned int* adjL = (unsigned int*)smem3;
  float* s2L = (float*)(smem3 + 8448);
  char* bufs = (char*)(smem3 + 42240);
  const int t = threadIdx.x;
  const int wave = t >> 6, lane = t & 63;
  const int blk = blockIdx.x;
  const int g = blk >> 8, b = (blk >> 6) & 3;
  const int i0 = (blk & 63) * 32;
  const int gb = g * 4 + b;
  const int* adj = (g ? adjB : adjA) + (b * NN + i0) * NN;
  K3_PROLOGUE
  __syncthreads();
  const int h = wave & 3;
  const int jhalf = wave >> 2;
  const int jlo = jhalf * 1024;
  const int i = lane & 31;
  const int jslot = lane >> 5;
  const float sc1v = (s1w[(gb * 4 + h) * NN + i0 + i] + attb[h]) * LOG2E;
  const char* rdb = bufs + wave * 4096 + lane * 16;
  f32x16 acc = {0.f, 0.f, 0.f, 0.f, 0.f, 0.f, 0.f, 0.f,
                0.f, 0.f, 0.f, 0.f, 0.f, 0.f, 0.f, 0.f};
  float den = 0.f;
  for (int rep = 0; rep < 4; ++rep) {
#pragma unroll 4
    for (int m = 0; m < 64; ++m) {
      const bf16x8 bcur = *(const bf16x8*)(rdb + (m & 3) * 1024);
      K3_SCORE_BODY(m)
      acc = __builtin_amdgcn_mfma_f32_32x32x16_bf16(af.v, bcur, acc, 0, 0, 0);
    }
  }
  po[blk * 512 + t] = acc[0] + acc[7] + acc[15] + den;
}

// ---------------------------------------------------------------------------
// PROBE E: same as D but WITH the vmcnt clobbers, x4
// ---------------------------------------------------------------------------
__global__ __launch_bounds__(512) void k3p_chainw(const float* __restrict__ s1w,
                                                  const float* __restrict__ s2w,
                                                  const int* __restrict__ adjA,
                                                  const int* __restrict__ adjB,
                                                  const float* __restrict__ attb,
                                                  float* __restrict__ po) {
  __shared__ __align__(16) unsigned char smem3[75008];
  unsigned int* adjL = (unsigned int*)smem3;
  float* s2L = (float*)(smem3 + 8448);
  char* bufs = (char*)(smem3 + 42240);
  const int t = threadIdx.x;
  const int wave = t >> 6, lane = t & 63;
  const int blk = blockIdx.x;
  const int g = blk >> 8, b = (blk >> 6) & 3;
  const int i0 = (blk & 63) * 32;
  const int gb = g * 4 + b;
  const int* adj = (g ? adjB : adjA) + (b * NN + i0) * NN;
  K3_PROLOGUE
  __syncthreads();
  const int h = wave & 3;
  const int jhalf = wave >> 2;
  const int jlo = jhalf * 1024;
  const int i = lane & 31;
  const int jslot = lane >> 5;
  const float sc1v = (s1w[(gb * 4 + h) * NN + i0 + i] + attb[h]) * LOG2E;
  const char* rdb = bufs + wave * 4096 + lane * 16;
  f32x16 acc = {0.f, 0.f, 0.f, 0.f, 0.f, 0.f, 0.f, 0.f,
                0.f, 0.f, 0.f, 0.f, 0.f, 0.f, 0.f, 0.f};
  float den = 0.f;
  for (int rep = 0; rep < 4; ++rep) {
#pragma unroll 4
    for (int m = 0; m < 64; ++m) {
      waitv<3>();
      const bf16x8 bcur = *(const bf16x8*)(rdb + (m & 3) * 1024);
      K3_SCORE_BODY(m)
      acc = __builtin_amdgcn_mfma_f32_32x32x16_bf16(af.v, bcur, acc, 0, 0, 0);
    }
  }
  po[blk * 512 + t] = acc[0] + acc[7] + acc[15] + den;
}

// ---------------------------------------------------------------------------
// K4h / K4a / K4b / K4c / K4d / K5 (unchanged)
// ---------------------------------------------------------------------------
__global__ __launch_bounds__(256) void k4h_gge(const float* __restrict__ a_in,
                                               const float* __restrict__ b_in,
                                               const float* __restrict__ ggeW1,
                                               const float* __restrict__ ggeb1,
                                               const float* __restrict__ ggeW2,
                                               const float* __restrict__ ggeb2,
                                               float* __restrict__ hvbuf,
                                               float* __restrict__ e) {
  __shared__ float inL[512];
  __shared__ float h1L[128];
  const int t = threadIdx.x;
  const int wave = t >> 6, lane = t & 63;
  const int g = blockIdx.x >> 2, b = blockIdx.x & 3;
  const int gb2 = g * 4 + b;
  const float* inp = (g ? b_in : a_in) + b * 512;
  if (t < 128) *(float4*)&inL[t * 4] = *(const float4*)&inp[t * 4];
  __syncthreads();
  for (int p = 0; p < 16; ++p) {
    const int o0 = p * 8 + wave * 2;
    const float* w0 = &ggeW1[o0 * 512 + lane * 8];
    const float* w1 = &ggeW1[(o0 + 1) * 512 + lane * 8];
    const float4 i0v = *(const float4*)&inL[lane * 8];
    const float4 i1v = *(const float4*)&inL[lane * 8 + 4];
    float s0 = dot4(*(const float4*)&w0[0], i0v) + dot4(*(const float4*)&w0[4], i1v);
    float s1v = dot4(*(const float4*)&w1[0], i0v) + dot4(*(const float4*)&w1[4], i1v);
#pragma unroll
    for (int s = 1; s < 64; s <<= 1) { s0 += __shfl_xor(s0, s); s1v += __shfl_xor(s1v, s); }
    if (lane == 0) {
      h1L[o0] = fmaxf(s0 + ggeb1[o0], 0.f);
      h1L[o0 + 1] = fmaxf(s1v + ggeb1[o0 + 1], 0.f);
    }
  }
  __syncthreads();
  for (int p = 0; p < 16; ++p) {
    const int o0 = p * 8 + wave * 2;
    const float2 w0 = *(const float2*)&ggeW2[o0 * 128 + lane * 2];
    const float2 w1 = *(const float2*)&ggeW2[(o0 + 1) * 128 + lane * 2];
    const float2 hvv = *(const float2*)&h1L[lane * 2];
    float s0 = w0.x * hvv.x + w0.y * hvv.y;
    float s1v = w1.x * hvv.x + w1.y * hvv.y;
#pragma unroll
    for (int s = 1; s < 64; s <<= 1) { s0 += __shfl_xor(s0, s); s1v += __shfl_xor(s1v, s); }
    if (lane == 0) {
      const float v0 = fmaxf(s0 + ggeb2[o0], 0.f);
      const float v1 = fmaxf(s1v + ggeb2[o0 + 1], 0.f);
      hvbuf[gb2 * 128 + o0] = v0;
      hvbuf[gb2 * 128 + o0 + 1] = v1;
      e[gb2 * 256 + o0] = v0;
      e[gb2 * 256 + o0 + 1] = v1;
    }
  }
}

__global__ __launch_bounds__(256) void k4a_logits(const float* __restrict__ G,
                                                  const float* __restrict__ hv,
                                                  float* __restrict__ lg) {
  const int t = threadIdx.x;
  const int wave = t >> 6, lane = t & 63;
  const int gb = blockIdx.x >> 4, chunk = blockIdx.x & 15;
  const float2 hvv = *(const float2*)&hv[gb * 128 + lane * 2];
  const float* Gb = G + gb * NN * 128;
  const int nbase = chunk * 128 + wave * 32;
  for (int q = 0; q < 32; ++q) {
    const int n = nbase + q;
    const float2 gv = *(const float2*)&Gb[n * 128 + lane * 2];
    float part = gv.x * hvv.x + gv.y * hvv.y;
#pragma unroll
    for (int s = 1; s < 64; s <<= 1) part += __shfl_xor(part, s);
    if (lane == 0) lg[gb * NN + n] = part;
  }
}

__global__ __launch_bounds__(256) void k4b_reduce(const float* __restrict__ lg,
                                                  float* __restrict__ mz) {
  __shared__ float red[256];
  const int t = threadIdx.x;
  const int gb = blockIdx.x;
  const float* l = lg + gb * NN;
  float m = -1e30f;
  for (int n = t; n < NN; n += 256) m = fmaxf(m, l[n]);
  red[t] = m; __syncthreads();
#pragma unroll
  for (int s = 128; s > 0; s >>= 1) {
    if (t < s) red[t] = fmaxf(red[t], red[t + s]);
    __syncthreads();
  }
  const float mx = red[0]; __syncthreads();
  float z = 0.f;
  for (int n = t; n < NN; n += 256) z += __expf(l[n] - mx);
  red[t] = z; __syncthreads();
#pragma unroll
  for (int s = 128; s > 0; s >>= 1) {
    if (t < s) red[t] += red[t + s];
    __syncthreads();
  }
  if (t == 0) { mz[gb * 2] = mx; mz[gb * 2 + 1] = red[0]; }
}

__global__ __launch_bounds__(256) void k4c_wsum(const float* __restrict__ G,
                                                const float* __restrict__ lg,
                                                const float* __restrict__ mz,
                                                float* __restrict__ wsum) {
  __shared__ float pL[128];
  __shared__ float red[2][128];
  const int t = threadIdx.x;
  const int gb = blockIdx.x >> 4, chunk = blockIdx.x & 15;
  const float mx = mz[gb * 2];
  if (t < 128) pL[t] = __expf(lg[gb * NN + chunk * 128 + t] - mx);
  __syncthreads();
  const int d = t & 127, half = t >> 7;
  const float* Gb = G + (gb * NN + chunk * 128 + half * 64) * 128;
  float acc = 0.f;
  for (int q = 0; q < 64; ++q) acc += pL[half * 64 + q] * Gb[q * 128 + d];
  red[half][d] = acc;
  __syncthreads();
  if (t < 128) wsum[(gb * 16 + chunk) * 128 + t] = red[0][t] + red[1][t];
}

__global__ __launch_bounds__(128) void k4d_final(const float* __restrict__ wsum,
                                                 const float* __restrict__ mz,
                                                 float* __restrict__ e) {
  const int t = threadIdx.x;
  const int gb = blockIdx.x;
  float s = 0.f;
#pragma unroll
  for (int c = 0; c < 16; ++c) s += wsum[(gb * 16 + c) * 128 + t];
  e[gb * 256 + 128 + t] = s / mz[gb * 2 + 1];
}

__global__ __launch_bounds__(256) void k5_led(const float* __restrict__ e,
                                              const float* __restrict__ convW,
                                              const float* __restrict__ convb,
                                              const float* __restrict__ ledW1,
                                              const float* __restrict__ ledb1,
                                              const float* __restrict__ ledW2,
                                              const float* __restrict__ ledb2,
                                              float* __restrict__ out) {
  __shared__ float eaL[256], ebL[256], uL[512], xL[128], lgL[2];
  const int t = threadIdx.x;
  const int wave = t >> 6, lane = t & 63;
  const int bt = blockIdx.x;
  if (t < 64) {
    *(float4*)&eaL[t * 4] = *(const float4*)&e[bt * 256 + t * 4];
    *(float4*)&ebL[t * 4] = *(const float4*)&e[(4 + bt) * 256 + t * 4];
  }
  __syncthreads();
  uL[256 + t] = eaL[t] - ebL[t];
  const float4 ea4 = *(const float4*)&eaL[lane * 4];
  const float4 eb4 = *(const float4*)&ebL[lane * 4];
  for (int p = 0; p < 32; ++p) {
    const int o0 = p * 8 + wave * 2;
    const float4 w0 = *(const float4*)&convW[o0 * 256 + lane * 4];
    const float4 w1 = *(const float4*)&convW[(o0 + 1) * 256 + lane * 4];
    float sa0 = dot4(w0, ea4), sb0 = dot4(w0, eb4);
    float sa1 = dot4(w1, ea4), sb1 = dot4(w1, eb4);
#pragma unroll
    for (int s = 1; s < 64; s <<= 1) {
      sa0 += __shfl_xor(sa0, s); sb0 += __shfl_xor(sb0, s);
      sa1 += __shfl_xor(sa1, s); sb1 += __shfl_xor(sb1, s);
    }
    if (lane == 0) {
      const float c0 = convb[o0], c1 = convb[o0 + 1];
      uL[o0] = fmaxf(sa0 + c0, sb0 + c0);
      uL[o0 + 1] = fmaxf(sa1 + c1, sb1 + c1);
    }
  }
  __syncthreads();
  for (int p = 0; p < 16; ++p) {
    const int o0 = p * 8 + wave * 2;
    const float* w0 = &ledW1[o0 * 512 + lane * 8];
    const float* w1 = &ledW1[(o0 + 1) * 512 + lane * 8];
    const float4 u0 = *(const float4*)&uL[lane * 8];
    const float4 u1 = *(const float4*)&uL[lane * 8 + 4];
    float s0 = dot4(*(const float4*)&w0[0], u0) + dot4(*(const float4*)&w0[4], u1);
    float s1v = dot4(*(const float4*)&w1[0], u0) + dot4(*(const float4*)&w1[4], u1);
#pragma unroll
    for (int s = 1; s < 64; s <<= 1) { s0 += __shfl_xor(s0, s); s1v += __shfl_xor(s1v, s); }
    if (lane == 0) {
      xL[o0] = fmaxf(s0 + ledb1[o0], 0.f);
      xL[o0 + 1] = fmaxf(s1v + ledb1[o0 + 1], 0.f);
    }
  }
  __syncthreads();
  if (wave < 2) {
    const float2 w = *(const float2*)&ledW2[wave * 128 + lane * 2];
    const float2 xv = *(const float2*)&xL[lane * 2];
    float s0 = w.x * xv.x + w.y * xv.y;
#pragma unroll
    for (int s = 1; s < 64; s <<= 1) s0 += __shfl_xor(s0, s);
    if (lane == 0) lgL[wave] = s0 + ledb2[wave];
  }
  __syncthreads();
  if (t == 0) {
    const float l0 = lgL[0], l1 = lgL[1];
    const float m = fmaxf(l0, l1);
    const float za = __expf(l0 - m) + __expf(l1 - m);
    const float lz = __logf(za);
    out[bt * 2 + 0] = l0 - m - lz;
    out[bt * 2 + 1] = l1 - m - lz;
  }
}

// ---------------------------------------------------------------------------
extern "C" void kernel_launch(void* const* d_in, const int* in_sizes, int n_in,
                              void* d_out, int out_size, void* d_ws, size_t ws_size,
                              hipStream_t stream) {
  (void)in_sizes; (void)n_in; (void)out_size; (void)ws_size;
  const float* a     = (const float*)d_in[0];
  const float* bioA  = (const float*)d_in[1];
  const int*   A     = (const int*)d_in[2];
  const float* b     = (const float*)d_in[3];
  const float* bioB  = (const float*)d_in[4];
  const int*   B     = (const int*)d_in[5];
  const float* initW = (const float*)d_in[6];
  const float* initb = (const float*)d_in[7];
  const float* projW = (const float*)d_in[8];
  const float* attw  = (const float*)d_in[9];
  const float* attb  = (const float*)d_in[10];
  const float* ggeW1 = (const float*)d_in[11];
  const float* ggeb1 = (const float*)d_in[12];
  const float* ggeW2 = (const float*)d_in[13];
  const float* ggeb2 = (const float*)d_in[14];
  const float* convW = (const float*)d_in[15];
  const float* convb = (const float*)d_in[16];
  const float* ledW1 = (const float*)d_in[17];
  const float* ledb1 = (const float*)d_in[18];
  const float* ledW2 = (const float*)d_in[19];
  const float* ledb2 = (const float*)d_in[20];

  float* ws = (float*)d_ws;
  float*          x    = ws;
  unsigned short* xhT2 = (unsigned short*)(ws + 2097152);
  float*          s1   = ws + 3145728;
  float*          s2   = ws + 3211264;
  float*          G    = ws + 3276800;
  float*          lg   = ws + 5373952;
  float*          wsum = ws + 5390336;
  float*          mz   = ws + 5406720;
  float*          hv   = ws + 5406736;
  float*          e    = ws + 5407760;
  float* out = (float*)d_out;

  k1_init<<<512, 256, 0, stream>>>(bioA, bioB, initW, initb, x);
  k2_proj<<<512, 256, 0, stream>>>(x, projW, attw, xhT2, s1, s2);
  k3_attn<<<512, 512, 0, stream>>>(xhT2, s1, s2, A, B, attb, x, G);
  k4h_gge<<<8, 256, 0, stream>>>(a, b, ggeW1, ggeb1, ggeW2, ggeb2, hv, e);
  k4a_logits<<<128, 256, 0, stream>>>(G, hv, lg);
  k4b_reduce<<<8, 256, 0, stream>>>(lg, mz);
  k4c_wsum<<<128, 256, 0, stream>>>(G, lg, mz, wsum);
  k4d_final<<<8, 128, 0, stream>>>(wsum, mz, e);
  k5_led<<<4, 256, 0, stream>>>(e, convW, convb, ledW1, ledb1, ledW2, ledb2, out);
  // ---- ablation probes (write only to dead ws region `x`; x is fully
  //      rewritten by k1 at the start of every replay) ----
  k3p_stage<<<512, 512, 0, stream>>>(s2, A, B, x);
  k3p_score<<<512, 512, 0, stream>>>(s1, s2, A, B, attb, x);
  k3p_chain<<<512, 512, 0, stream>>>(s1, s2, A, B, attb, x);
  k3p_chainw<<<512, 512, 0, stream>>>(s1, s2, A, B, attb, x);
}

// Round 10
// 178.190 us; speedup vs baseline: 4.0886x; 4.0886x over previous
//
#include <hip/hip_runtime.h>
#include <hip/hip_bf16.h>
#include <math.h>

#define NN 2048
#define NEG 0.2f
#define LOG2E 1.44269504f

typedef short bf16x8 __attribute__((ext_vector_type(8)));
typedef float f32x16 __attribute__((ext_vector_type(16)));

__device__ __forceinline__ float dot4(float4 a, float4 b) {
  return a.x * b.x + a.y * b.y + a.z * b.z + a.w * b.w;
}

__device__ __forceinline__ unsigned short bfbits(float f) {
  union { __hip_bfloat16 b; unsigned short u; } c;
  c.b = __float2bfloat16(f);
  return c.u;
}

// ---------------------------------------------------------------------------
// K1: x = bio @ initW^T + initb
// ---------------------------------------------------------------------------
__global__ __launch_bounds__(256) void k1_init(const float* __restrict__ bioA,
                                               const float* __restrict__ bioB,
                                               const float* __restrict__ W,
                                               const float* __restrict__ bias,
                                               float* __restrict__ xout) {
  __shared__ float As[32][36];
  __shared__ float Ws[32][132];
  const int t = threadIdx.x;
  const int m0 = blockIdx.x * 32;
  const float* A = (m0 < 8192) ? bioA : bioB;
  const int arow0 = (m0 < 8192) ? m0 : (m0 - 8192);
  const int og = t & 31, ig = t >> 5;
  float acc[4][4] = {};
  for (int kt = 0; kt < 256; kt += 32) {
    __syncthreads();
    {
      const int r = t >> 3, kq = t & 7;
      const float4 v = *(const float4*)&A[(arow0 + r) * 256 + kt + kq * 4];
      As[kq * 4 + 0][r] = v.x; As[kq * 4 + 1][r] = v.y;
      As[kq * 4 + 2][r] = v.z; As[kq * 4 + 3][r] = v.w;
    }
#pragma unroll
    for (int u = 0; u < 4; ++u) {
      const int f = u * 256 + t;
      const int o = f >> 3, kq = f & 7;
      const float4 v = *(const float4*)&W[o * 256 + kt + kq * 4];
      Ws[kq * 4 + 0][o] = v.x; Ws[kq * 4 + 1][o] = v.y;
      Ws[kq * 4 + 2][o] = v.z; Ws[kq * 4 + 3][o] = v.w;
    }
    __syncthreads();
#pragma unroll
    for (int kk = 0; kk < 32; ++kk) {
      const float4 a4 = *(const float4*)&As[kk][ig * 4];
      const float4 w4 = *(const float4*)&Ws[kk][og * 4];
      const float av[4] = {a4.x, a4.y, a4.z, a4.w};
      const float wv[4] = {w4.x, w4.y, w4.z, w4.w};
#pragma unroll
      for (int ii = 0; ii < 4; ++ii)
#pragma unroll
        for (int jj = 0; jj < 4; ++jj) acc[ii][jj] += av[ii] * wv[jj];
    }
  }
  const float4 b4 = *(const float4*)&bias[og * 4];
#pragma unroll
  for (int ii = 0; ii < 4; ++ii) {
    const int row = m0 + ig * 4 + ii;
    float4 o4;
    o4.x = acc[ii][0] + b4.x; o4.y = acc[ii][1] + b4.y;
    o4.z = acc[ii][2] + b4.z; o4.w = acc[ii][3] + b4.w;
    *(float4*)&xout[row * 128 + og * 4] = o4;
  }
}

// ---------------------------------------------------------------------------
// K2: y = x @ projW^T ; xhT2 bf16 tile-major [gb][h][m][jslot][k][j8]; s1,s2
// ---------------------------------------------------------------------------
__global__ __launch_bounds__(256) void k2_proj(const float* __restrict__ x,
                                               const float* __restrict__ W,
                                               const float* __restrict__ attw,
                                               unsigned short* __restrict__ xhT2,
                                               float* __restrict__ s1,
                                               float* __restrict__ s2) {
  __shared__ float As[32][36];
  __shared__ float Ws[32][132];
  const int t = threadIdx.x;
  const int m0 = blockIdx.x * 32;
  const int og = t & 31, ig = t >> 5;
  float acc[4][4] = {};
  for (int kt = 0; kt < 128; kt += 32) {
    __syncthreads();
    {
      const int r = t >> 3, kq = t & 7;
      const float4 v = *(const float4*)&x[(m0 + r) * 128 + kt + kq * 4];
      As[kq * 4 + 0][r] = v.x; As[kq * 4 + 1][r] = v.y;
      As[kq * 4 + 2][r] = v.z; As[kq * 4 + 3][r] = v.w;
    }
#pragma unroll
    for (int u = 0; u < 4; ++u) {
      const int f = u * 256 + t;
      const int o = f >> 3, kq = f & 7;
      const float4 v = *(const float4*)&W[o * 128 + kt + kq * 4];
      Ws[kq * 4 + 0][o] = v.x; Ws[kq * 4 + 1][o] = v.y;
      Ws[kq * 4 + 2][o] = v.z; Ws[kq * 4 + 3][o] = v.w;
    }
    __syncthreads();
#pragma unroll
    for (int kk = 0; kk < 32; ++kk) {
      const float4 a4 = *(const float4*)&As[kk][ig * 4];
      const float4 w4 = *(const float4*)&Ws[kk][og * 4];
      const float av[4] = {a4.x, a4.y, a4.z, a4.w};
      const float wv[4] = {w4.x, w4.y, w4.z, w4.w};
#pragma unroll
      for (int ii = 0; ii < 4; ++ii)
#pragma unroll
        for (int jj = 0; jj < 4; ++jj) acc[ii][jj] += av[ii] * wv[jj];
    }
  }
  const int h = og >> 3;
  const int k4i = (og & 7) * 4;
  const int g = m0 >> 13;
  const int bb = (m0 >> 11) & 3;
  const int gb = g * 4 + bb;
  const int n0 = (m0 & 2047) + ig * 4;
  const float4 w1 = *(const float4*)&attw[h * 64 + k4i];
  const float4 w2 = *(const float4*)&attw[h * 64 + 32 + k4i];
  float p1[4], p2[4];
#pragma unroll
  for (int ii = 0; ii < 4; ++ii) {
    float4 v;
    v.x = acc[ii][0]; v.y = acc[ii][1]; v.z = acc[ii][2]; v.w = acc[ii][3];
    p1[ii] = dot4(v, w1);
    p2[ii] = dot4(v, w2);
  }
  {
    const int mtile = n0 >> 4, jslot = (n0 >> 3) & 1, j8 = n0 & 7;
    const int base2 = ((((gb * 4 + h) * 128 + mtile) * 2 + jslot) * 32) * 8 + j8;
#pragma unroll
    for (int jj = 0; jj < 4; ++jj) {
      const int kin = k4i + jj;
      ushort4 u;
      u.x = bfbits(acc[0][jj]); u.y = bfbits(acc[1][jj]);
      u.z = bfbits(acc[2][jj]); u.w = bfbits(acc[3][jj]);
      *(ushort4*)&xhT2[base2 + kin * 8] = u;
    }
  }
#pragma unroll
  for (int s = 1; s < 8; s <<= 1) {
#pragma unroll
    for (int ii = 0; ii < 4; ++ii) {
      p1[ii] += __shfl_xor(p1[ii], s);
      p2[ii] += __shfl_xor(p2[ii], s);
    }
  }
  if ((og & 7) == 0) {
#pragma unroll
    for (int ii = 0; ii < 4; ++ii) {
      s1[(gb * 4 + h) * NN + n0 + ii] = p1[ii];
      s2[(gb * 4 + h) * NN + n0 + ii] = p2[ii];
    }
  }
}

// shared prologue body (s2 staging + deep-batched adjacency ballot-pack)
#define K3_PROLOGUE                                                           \
  {                                                                           \
    const float* s2g = s2w + gb * 4 * NN;                                     \
    _Pragma("unroll")                                                         \
    for (int u = 0; u < 4; ++u) {                                             \
      const int idx = u * 2048 + t * 4;                                       \
      float4 v = *(const float4*)&s2g[idx];                                   \
      v.x *= LOG2E; v.y *= LOG2E; v.z *= LOG2E; v.w *= LOG2E;                 \
      *(float4*)&s2L[idx] = v;                                                \
    }                                                                         \
  }                                                                           \
  _Pragma("unroll")                                                           \
  for (int r4 = 0; r4 < 4; ++r4) {                                            \
    const int r = wave * 4 + r4;                                              \
    const int* arow = adj + r * NN;                                           \
    int av[32];                                                               \
    _Pragma("unroll")                                                         \
    for (int w = 0; w < 32; ++w) av[w] = arow[w * 64 + lane];                 \
    _Pragma("unroll")                                                         \
    for (int w = 0; w < 32; ++w) {                                            \
      const unsigned long long mm = __ballot(av[w] > 0);                      \
      if (lane < 2) adjL[r * 66 + 2 * w + lane] = (unsigned int)(mm >> (32 * lane)); \
    }                                                                         \
  }

#define K3_SCORE_BODY(MM)                                                     \
    const int j0 = jlo + 16 * (MM) + jslot * 8;                               \
    const unsigned int wbits = adjL[i * 66 + ((jlo + 16 * (MM)) >> 5)];       \
    const unsigned int bits8 = wbits >> ((((MM) & 1) * 16) + jslot * 8);      \
    const float4 s2a = *(const float4*)&s2L[h * 2048 + j0];                   \
    const float4 s2b = *(const float4*)&s2L[h * 2048 + j0 + 4];               \
    const float sv[8] = {s2a.x, s2a.y, s2a.z, s2a.w,                          \
                         s2b.x, s2b.y, s2b.z, s2b.w};                         \
    union { bf16x8 v; unsigned short u[8]; } af;                              \
    float dsum = 0.f;                                                         \
    _Pragma("unroll")                                                         \
    for (int e = 0; e < 8; ++e) {                                             \
      float s = sc1v + sv[e];                                                 \
      s = fmaxf(s, NEG * s);                                                  \
      float pe = __builtin_amdgcn_exp2f(s);                                   \
      pe = ((bits8 >> e) & 1u) ? pe : 0.f;                                    \
      af.u[e] = bfbits(pe);                                                   \
      dsum += pe;                                                             \
    }                                                                         \
    den += dsum;

// ---------------------------------------------------------------------------
// K3: GAT attention via MFMA. block = (g,b, 32-row i-tile), 512 threads.
// wave = (jhalf, head). B-frags: double-batched (2x4) plain loads held apart
// from their uses by sched_barrier(0) — compiler cannot collapse the
// prefetch distance, and inserts its own counted waitcnts (no inline asm).
// LDS: adjL [0:8448) | s2L [8448:41216) | denR [41216:42240); accR aliases
// [0:16640) after the loop (barrier-separated).
// ---------------------------------------------------------------------------
__global__ __launch_bounds__(512) void k3_attn(const unsigned short* __restrict__ xhT2,
                                               const float* __restrict__ s1w,
                                               const float* __restrict__ s2w,
                                               const int* __restrict__ adjA,
                                               const int* __restrict__ adjB,
                                               const float* __restrict__ attb,
                                               const float* __restrict__ x,
                                               float* __restrict__ G) {
  __shared__ __align__(16) unsigned char smem3[42240];
  unsigned int* adjL = (unsigned int*)smem3;
  float* s2L = (float*)(smem3 + 8448);
  float* denR = (float*)(smem3 + 41216);
  float* accR = (float*)smem3;

  const int t = threadIdx.x;
  const int wave = t >> 6, lane = t & 63;
  const int blk = blockIdx.x;
  const int g = blk >> 8, b = (blk >> 6) & 3;
  const int i0 = (blk & 63) * 32;
  const int gb = g * 4 + b;
  const int* adj = (g ? adjB : adjA) + (b * NN + i0) * NN;
  K3_PROLOGUE
  __syncthreads();

  const int h = wave & 3;
  const int jhalf = wave >> 2;
  const int jlo = jhalf * 1024;
  const int i = lane & 31;
  const int jslot = lane >> 5;
  const float sc1v = (s1w[(gb * 4 + h) * NN + i0 + i] + attb[h]) * LOG2E;
  const unsigned short* bbase = xhT2 + (gb * 4 + h) * 65536 + jhalf * 32768 + lane * 8;
  f32x16 acc = {0.f, 0.f, 0.f, 0.f, 0.f, 0.f, 0.f, 0.f,
                0.f, 0.f, 0.f, 0.f, 0.f, 0.f, 0.f, 0.f};
  float den = 0.f;

#define K3_CSTEP(RB, MM)                                                      \
  {                                                                           \
    K3_SCORE_BODY(MM)                                                         \
    acc = __builtin_amdgcn_mfma_f32_32x32x16_bf16(af.v, RB, acc, 0, 0, 0);    \
  }

  bf16x8 ba0 = *(const bf16x8*)&bbase[0 * 512];
  bf16x8 ba1 = *(const bf16x8*)&bbase[1 * 512];
  bf16x8 ba2 = *(const bf16x8*)&bbase[2 * 512];
  bf16x8 ba3 = *(const bf16x8*)&bbase[3 * 512];
  __builtin_amdgcn_sched_barrier(0);
  for (int mb = 0; mb < 64; mb += 8) {
    // issue next 4 (frags mb+4..mb+7), then compute frags mb..mb+3
    bf16x8 bb0 = *(const bf16x8*)&bbase[(mb + 4) * 512];
    bf16x8 bb1 = *(const bf16x8*)&bbase[(mb + 5) * 512];
    bf16x8 bb2 = *(const bf16x8*)&bbase[(mb + 6) * 512];
    bf16x8 bb3 = *(const bf16x8*)&bbase[(mb + 7) * 512];
    __builtin_amdgcn_sched_barrier(0);
    K3_CSTEP(ba0, mb + 0)
    K3_CSTEP(ba1, mb + 1)
    K3_CSTEP(ba2, mb + 2)
    K3_CSTEP(ba3, mb + 3)
    __builtin_amdgcn_sched_barrier(0);
    // issue frags mb+8..mb+11 (skip past end), then compute mb+4..mb+7
    if (mb < 56) {
      ba0 = *(const bf16x8*)&bbase[(mb + 8) * 512];
      ba1 = *(const bf16x8*)&bbase[(mb + 9) * 512];
      ba2 = *(const bf16x8*)&bbase[(mb + 10) * 512];
      ba3 = *(const bf16x8*)&bbase[(mb + 11) * 512];
    }
    __builtin_amdgcn_sched_barrier(0);
    K3_CSTEP(bb0, mb + 4)
    K3_CSTEP(bb1, mb + 5)
    K3_CSTEP(bb2, mb + 6)
    K3_CSTEP(bb3, mb + 7)
    __builtin_amdgcn_sched_barrier(0);
  }
#undef K3_CSTEP

  den += __shfl_xor(den, 32);
  if (lane < 32) denR[(h * 2 + jhalf) * 32 + lane] = den;
  __syncthreads();
  if (jhalf == 1) {
#pragma unroll
    for (int r = 0; r < 16; ++r) accR[(h * 16 + r) * 65 + lane] = acc[r];
  }
  __syncthreads();
  if (jhalf == 0) {
#pragma unroll
    for (int r = 0; r < 16; ++r) {
      const int row = (r & 3) + 8 * (r >> 2) + 4 * jslot;
      const float dinv = 1.f / (denR[(h * 2 + 0) * 32 + row] + denR[(h * 2 + 1) * 32 + row]);
      const int off = (gb * NN + i0 + row) * 128 + h * 32 + i;
      const float av2 = acc[r] + accR[(h * 16 + r) * 65 + lane];
      G[off] = fmaxf(av2 * dinv, 0.f) + x[off];
    }
  }
}

// ---------------------------------------------------------------------------
// K4h / K4a / K4b / K4c / K4d / K5 (unchanged)
// ---------------------------------------------------------------------------
__global__ __launch_bounds__(256) void k4h_gge(const float* __restrict__ a_in,
                                               const float* __restrict__ b_in,
                                               const float* __restrict__ ggeW1,
                                               const float* __restrict__ ggeb1,
                                               const float* __restrict__ ggeW2,
                                               const float* __restrict__ ggeb2,
                                               float* __restrict__ hvbuf,
                                               float* __restrict__ e) {
  __shared__ float inL[512];
  __shared__ float h1L[128];
  const int t = threadIdx.x;
  const int wave = t >> 6, lane = t & 63;
  const int g = blockIdx.x >> 2, b = blockIdx.x & 3;
  const int gb2 = g * 4 + b;
  const float* inp = (g ? b_in : a_in) + b * 512;
  if (t < 128) *(float4*)&inL[t * 4] = *(const float4*)&inp[t * 4];
  __syncthreads();
  for (int p = 0; p < 16; ++p) {
    const int o0 = p * 8 + wave * 2;
    const float* w0 = &ggeW1[o0 * 512 + lane * 8];
    const float* w1 = &ggeW1[(o0 + 1) * 512 + lane * 8];
    const float4 i0v = *(const float4*)&inL[lane * 8];
    const float4 i1v = *(const float4*)&inL[lane * 8 + 4];
    float s0 = dot4(*(const float4*)&w0[0], i0v) + dot4(*(const float4*)&w0[4], i1v);
    float s1v = dot4(*(const float4*)&w1[0], i0v) + dot4(*(const float4*)&w1[4], i1v);
#pragma unroll
    for (int s = 1; s < 64; s <<= 1) { s0 += __shfl_xor(s0, s); s1v += __shfl_xor(s1v, s); }
    if (lane == 0) {
      h1L[o0] = fmaxf(s0 + ggeb1[o0], 0.f);
      h1L[o0 + 1] = fmaxf(s1v + ggeb1[o0 + 1], 0.f);
    }
  }
  __syncthreads();
  for (int p = 0; p < 16; ++p) {
    const int o0 = p * 8 + wave * 2;
    const float2 w0 = *(const float2*)&ggeW2[o0 * 128 + lane * 2];
    const float2 w1 = *(const float2*)&ggeW2[(o0 + 1) * 128 + lane * 2];
    const float2 hvv = *(const float2*)&h1L[lane * 2];
    float s0 = w0.x * hvv.x + w0.y * hvv.y;
    float s1v = w1.x * hvv.x + w1.y * hvv.y;
#pragma unroll
    for (int s = 1; s < 64; s <<= 1) { s0 += __shfl_xor(s0, s); s1v += __shfl_xor(s1v, s); }
    if (lane == 0) {
      const float v0 = fmaxf(s0 + ggeb2[o0], 0.f);
      const float v1 = fmaxf(s1v + ggeb2[o0 + 1], 0.f);
      hvbuf[gb2 * 128 + o0] = v0;
      hvbuf[gb2 * 128 + o0 + 1] = v1;
      e[gb2 * 256 + o0] = v0;
      e[gb2 * 256 + o0 + 1] = v1;
    }
  }
}

__global__ __launch_bounds__(256) void k4a_logits(const float* __restrict__ G,
                                                  const float* __restrict__ hv,
                                                  float* __restrict__ lg) {
  const int t = threadIdx.x;
  const int wave = t >> 6, lane = t & 63;
  const int gb = blockIdx.x >> 4, chunk = blockIdx.x & 15;
  const float2 hvv = *(const float2*)&hv[gb * 128 + lane * 2];
  const float* Gb = G + gb * NN * 128;
  const int nbase = chunk * 128 + wave * 32;
  for (int q = 0; q < 32; ++q) {
    const int n = nbase + q;
    const float2 gv = *(const float2*)&Gb[n * 128 + lane * 2];
    float part = gv.x * hvv.x + gv.y * hvv.y;
#pragma unroll
    for (int s = 1; s < 64; s <<= 1) part += __shfl_xor(part, s);
    if (lane == 0) lg[gb * NN + n] = part;
  }
}

__global__ __launch_bounds__(256) void k4b_reduce(const float* __restrict__ lg,
                                                  float* __restrict__ mz) {
  __shared__ float red[256];
  const int t = threadIdx.x;
  const int gb = blockIdx.x;
  const float* l = lg + gb * NN;
  float m = -1e30f;
  for (int n = t; n < NN; n += 256) m = fmaxf(m, l[n]);
  red[t] = m; __syncthreads();
#pragma unroll
  for (int s = 128; s > 0; s >>= 1) {
    if (t < s) red[t] = fmaxf(red[t], red[t + s]);
    __syncthreads();
  }
  const float mx = red[0]; __syncthreads();
  float z = 0.f;
  for (int n = t; n < NN; n += 256) z += __expf(l[n] - mx);
  red[t] = z; __syncthreads();
#pragma unroll
  for (int s = 128; s > 0; s >>= 1) {
    if (t < s) red[t] += red[t + s];
    __syncthreads();
  }
  if (t == 0) { mz[gb * 2] = mx; mz[gb * 2 + 1] = red[0]; }
}

__global__ __launch_bounds__(256) void k4c_wsum(const float* __restrict__ G,
                                                const float* __restrict__ lg,
                                                const float* __restrict__ mz,
                                                float* __restrict__ wsum) {
  __shared__ float pL[128];
  __shared__ float red[2][128];
  const int t = threadIdx.x;
  const int gb = blockIdx.x >> 4, chunk = blockIdx.x & 15;
  const float mx = mz[gb * 2];
  if (t < 128) pL[t] = __expf(lg[gb * NN + chunk * 128 + t] - mx);
  __syncthreads();
  const int d = t & 127, half = t >> 7;
  const float* Gb = G + (gb * NN + chunk * 128 + half * 64) * 128;
  float acc = 0.f;
  for (int q = 0; q < 64; ++q) acc += pL[half * 64 + q] * Gb[q * 128 + d];
  red[half][d] = acc;
  __syncthreads();
  if (t < 128) wsum[(gb * 16 + chunk) * 128 + t] = red[0][t] + red[1][t];
}

__global__ __launch_bounds__(128) void k4d_final(const float* __restrict__ wsum,
                                                 const float* __restrict__ mz,
                                                 float* __restrict__ e) {
  const int t = threadIdx.x;
  const int gb = blockIdx.x;
  float s = 0.f;
#pragma unroll
  for (int c = 0; c < 16; ++c) s += wsum[(gb * 16 + c) * 128 + t];
  e[gb * 256 + 128 + t] = s / mz[gb * 2 + 1];
}

__global__ __launch_bounds__(256) void k5_led(const float* __restrict__ e,
                                              const float* __restrict__ convW,
                                              const float* __restrict__ convb,
                                              const float* __restrict__ ledW1,
                                              const float* __restrict__ ledb1,
                                              const float* __restrict__ ledW2,
                                              const float* __restrict__ ledb2,
                                              float* __restrict__ out) {
  __shared__ float eaL[256], ebL[256], uL[512], xL[128], lgL[2];
  const int t = threadIdx.x;
  const int wave = t >> 6, lane = t & 63;
  const int bt = blockIdx.x;
  if (t < 64) {
    *(float4*)&eaL[t * 4] = *(const float4*)&e[bt * 256 + t * 4];
    *(float4*)&ebL[t * 4] = *(const float4*)&e[(4 + bt) * 256 + t * 4];
  }
  __syncthreads();
  uL[256 + t] = eaL[t] - ebL[t];
  const float4 ea4 = *(const float4*)&eaL[lane * 4];
  const float4 eb4 = *(const float4*)&ebL[lane * 4];
  for (int p = 0; p < 32; ++p) {
    const int o0 = p * 8 + wave * 2;
    const float4 w0 = *(const float4*)&convW[o0 * 256 + lane * 4];
    const float4 w1 = *(const float4*)&convW[(o0 + 1) * 256 + lane * 4];
    float sa0 = dot4(w0, ea4), sb0 = dot4(w0, eb4);
    float sa1 = dot4(w1, ea4), sb1 = dot4(w1, eb4);
#pragma unroll
    for (int s = 1; s < 64; s <<= 1) {
      sa0 += __shfl_xor(sa0, s); sb0 += __shfl_xor(sb0, s);
      sa1 += __shfl_xor(sa1, s); sb1 += __shfl_xor(sb1, s);
    }
    if (lane == 0) {
      const float c0 = convb[o0], c1 = convb[o0 + 1];
      uL[o0] = fmaxf(sa0 + c0, sb0 + c0);
      uL[o0 + 1] = fmaxf(sa1 + c1, sb1 + c1);
    }
  }
  __syncthreads();
  for (int p = 0; p < 16; ++p) {
    const int o0 = p * 8 + wave * 2;
    const float* w0 = &ledW1[o0 * 512 + lane * 8];
    const float* w1 = &ledW1[(o0 + 1) * 512 + lane * 8];
    const float4 u0 = *(const float4*)&uL[lane * 8];
    const float4 u1 = *(const float4*)&uL[lane * 8 + 4];
    float s0 = dot4(*(const float4*)&w0[0], u0) + dot4(*(const float4*)&w0[4], u1);
    float s1v = dot4(*(const float4*)&w1[0], u0) + dot4(*(const float4*)&w1[4], u1);
#pragma unroll
    for (int s = 1; s < 64; s <<= 1) { s0 += __shfl_xor(s0, s); s1v += __shfl_xor(s1v, s); }
    if (lane == 0) {
      xL[o0] = fmaxf(s0 + ledb1[o0], 0.f);
      xL[o0 + 1] = fmaxf(s1v + ledb1[o0 + 1], 0.f);
    }
  }
  __syncthreads();
  if (wave < 2) {
    const float2 w = *(const float2*)&ledW2[wave * 128 + lane * 2];
    const float2 xv = *(const float2*)&xL[lane * 2];
    float s0 = w.x * xv.x + w.y * xv.y;
#pragma unroll
    for (int s = 1; s < 64; s <<= 1) s0 += __shfl_xor(s0, s);
    if (lane == 0) lgL[wave] = s0 + ledb2[wave];
  }
  __syncthreads();
  if (t == 0) {
    const float l0 = lgL[0], l1 = lgL[1];
    const float m = fmaxf(l0, l1);
    const float za = __expf(l0 - m) + __expf(l1 - m);
    const float lz = __logf(za);
    out[bt * 2 + 0] = l0 - m - lz;
    out[bt * 2 + 1] = l1 - m - lz;
  }
}

// ---------------------------------------------------------------------------
extern "C" void kernel_launch(void* const* d_in, const int* in_sizes, int n_in,
                              void* d_out, int out_size, void* d_ws, size_t ws_size,
                              hipStream_t stream) {
  (void)in_sizes; (void)n_in; (void)out_size; (void)ws_size;
  const float* a     = (const float*)d_in[0];
  const float* bioA  = (const float*)d_in[1];
  const int*   A     = (const int*)d_in[2];
  const float* b     = (const float*)d_in[3];
  const float* bioB  = (const float*)d_in[4];
  const int*   B     = (const int*)d_in[5];
  const float* initW = (const float*)d_in[6];
  const float* initb = (const float*)d_in[7];
  const float* projW = (const float*)d_in[8];
  const float* attw  = (const float*)d_in[9];
  const float* attb  = (const float*)d_in[10];
  const float* ggeW1 = (const float*)d_in[11];
  const float* ggeb1 = (const float*)d_in[12];
  const float* ggeW2 = (const float*)d_in[13];
  const float* ggeb2 = (const float*)d_in[14];
  const float* convW = (const float*)d_in[15];
  const float* convb = (const float*)d_in[16];
  const float* ledW1 = (const float*)d_in[17];
  const float* ledb1 = (const float*)d_in[18];
  const float* ledW2 = (const float*)d_in[19];
  const float* ledb2 = (const float*)d_in[20];

  float* ws = (float*)d_ws;
  float*          x    = ws;
  unsigned short* xhT2 = (unsigned short*)(ws + 2097152);
  float*          s1   = ws + 3145728;
  float*          s2   = ws + 3211264;
  float*          G    = ws + 3276800;
  float*          lg   = ws + 5373952;
  float*          wsum = ws + 5390336;
  float*          mz   = ws + 5406720;
  float*          hv   = ws + 5406736;
  float*          e    = ws + 5407760;
  float* out = (float*)d_out;

  k1_init<<<512, 256, 0, stream>>>(bioA, bioB, initW, initb, x);
  k2_proj<<<512, 256, 0, stream>>>(x, projW, attw, xhT2, s1, s2);
  k3_attn<<<512, 512, 0, stream>>>(xhT2, s1, s2, A, B, attb, x, G);
  k4h_gge<<<8, 256, 0, stream>>>(a, b, ggeW1, ggeb1, ggeW2, ggeb2, hv, e);
  k4a_logits<<<128, 256, 0, stream>>>(G, hv, lg);
  k4b_reduce<<<8, 256, 0, stream>>>(lg, mz);
  k4c_wsum<<<128, 256, 0, stream>>>(G, lg, mz, wsum);
  k4d_final<<<8, 128, 0, stream>>>(wsum, mz, e);
  k5_led<<<4, 256, 0, stream>>>(e, convW, convb, ledW1, ledb1, ledW2, ledb2, out);
}